// Round 2
// baseline (227.386 us; speedup 1.0000x reference)
//
#include <hip/hip_runtime.h>
#include <stdint.h>

// Problem constants
#define BATCH 32
#define LLEN  36864
#define CCH   16
#define DOUT  512
#define KW    24
#define LOUT  1536            // LLEN / KW
#define MROWS (BATCH * LOUT)  // 49152 windows
#define CK    384             // CCH * KW (inner dot length)
#define TWOK  48

typedef float fx4 __attribute__((ext_vector_type(4)));
typedef float f32x4 __attribute__((ext_vector_type(4)));
typedef __bf16 bf16x8 __attribute__((ext_vector_type(8)));
typedef uint32_t u32x4 __attribute__((ext_vector_type(4)));

// ---------------------------------------------------------------------------
// K0: weight transposition to j = k*16+c layout (bf16).
// ---------------------------------------------------------------------------
__global__ __launch_bounds__(256) void prep_kernel(
    const float* __restrict__ w_off, const float* __restrict__ w_def,
    __bf16* __restrict__ woff_b, __bf16* __restrict__ wdef_b)
{
    int idx = blockIdx.x * 256 + threadIdx.x;
    if (idx < TWOK * CK) {
        int o = idx / CK, rem = idx % CK;
        int k = rem >> 4, c = rem & 15;
        woff_b[idx] = (__bf16)w_off[o * CK + c * KW + k];
    }
    if (idx < DOUT * CK) {
        int d = idx / CK, rem = idx % CK;
        int k = rem >> 4, c = rem & 15;
        wdef_b[idx] = (__bf16)w_def[d * CK + c * KW + k];
    }
}

// ---------------------------------------------------------------------------
// K1: fully fused offsets + gather + GEMM.
// B (wdef) is identical for every block and fully L2-resident (393 KB), so
// LDS-staging it was pure overhead: 64 KB global_load_lds per K-chunk whose
// vmcnt(0) drain at __syncthreads serialized every wave every iteration
// (R0 counters: MfmaUtil 10%, VALUBusy 8%, HBM 29% -- every pipe idle).
// Now: B fragments read DIRECTLY from global (16 cols x 64 contiguous B per
// wave-load, L2-hit), As double-buffered (2 x 12 KB) so ONE __syncthreads
// per K-chunk suffices; with the DMA queue gone, vmcnt is naturally ~0 at
// each barrier (gather prefetch is consumed by the As-pack before it), so
// the barrier's implicit vmcnt(0) drain is cheap. setprio(1) around MFMAs.
// LDS: 56 KB (prologue WoffS/offS aliased over As[2] / above it).
// ---------------------------------------------------------------------------
#define BM 96
#define BN 512
#define BK 64

__global__ __launch_bounds__(512) void gemm_fused(
    const float* __restrict__ x, const __bf16* __restrict__ woff_b,
    const float* __restrict__ b_off, const __bf16* __restrict__ Bw,
    const float* __restrict__ bias, float* __restrict__ out)
{
    __shared__ char smem[57344];
    __bf16* WoffS = (__bf16*)smem;               // [48][392] prologue (37632 B)
    float*  offS  = (float*)(smem + 38144);      // [96][49]  prologue (18816 B)
    __bf16* As    = (__bf16*)smem;               // [2][96*64] = 24576 B, aliases
                                                 // WoffS (dead after prologue)

    const int t = threadIdx.x;
    const int m0 = blockIdx.x * BM;
    const int wave = t >> 6, lane = t & 63;
    const int quad = lane >> 4, l16 = lane & 15;
    const int wr = wave >> 2, wc = wave & 3;        // 2x4 waves: tile 48x128

    // gather ownership (threads 0..383): row mloc, k-slot k4 (+4 per chunk)
    const int mloc = t >> 2, k4 = t & 3;
    const int Mrow = m0 + mloc;
    const int b    = m0 / LOUT;                     // 1536 % 96 == 0
    const int lb   = Mrow - b * LOUT;
    const float* xb = x + (size_t)b * LLEN * CCH;

    // ---- prologue: stage woff ----
#pragma unroll
    for (int i = 0; i < 5; ++i) {
        int q = t + 512 * i;                        // 2304 16B chunks
        if (q < 2304) {
            int row = q / 48, cc = q - row * 48;
            *(u32x4*)&WoffS[row * 392 + cc * 8] =
                *(const u32x4*)&woff_b[row * CK + cc * 8];
        }
    }
    __syncthreads();

    // ---- prologue: offsets MFMA (waves 0..5 cover 96 rows) ----
    if (wave < 6) {
        const float* xr = x + (size_t)(m0 + wave * 16 + l16) * CK;
        f32x4 oacc[3] = {};
#pragma unroll
        for (int ks = 0; ks < 12; ++ks) {
            int k0 = ks * 32 + quad * 8;
            fx4 a0 = *(const fx4*)&xr[k0];
            fx4 a1 = *(const fx4*)&xr[k0 + 4];
            bf16x8 af;
            af[0] = (__bf16)a0.x; af[1] = (__bf16)a0.y;
            af[2] = (__bf16)a0.z; af[3] = (__bf16)a0.w;
            af[4] = (__bf16)a1.x; af[5] = (__bf16)a1.y;
            af[6] = (__bf16)a1.z; af[7] = (__bf16)a1.w;
#pragma unroll
            for (int j = 0; j < 3; ++j) {
                bf16x8 bf = *(const bf16x8*)&WoffS[(j * 16 + l16) * 392 + k0];
                oacc[j] = __builtin_amdgcn_mfma_f32_16x16x32_bf16(af, bf, oacc[j], 0, 0, 0);
            }
        }
        float bo[3];
#pragma unroll
        for (int j = 0; j < 3; ++j) bo[j] = b_off[j * 16 + l16];
#pragma unroll
        for (int j = 0; j < 3; ++j)
#pragma unroll
            for (int r = 0; r < 4; ++r)
                offS[(wave * 16 + quad * 4 + r) * 49 + j * 16 + l16] = oacc[j][r] + bo[j];
    }
    __syncthreads();

    // ---- prologue: pack this thread's 6 (dy,dx) pairs into regs ----
    uint32_t dxyr[6];
    if (t < 4 * BM) {
#pragma unroll
        for (int cc = 0; cc < 6; ++cc) {
            int kk = 4 * cc + k4;
            float dy = offS[mloc * 49 + 2 * kk];
            float dx = offS[mloc * 49 + 2 * kk + 1];
            union { __bf16 h[2]; uint32_t u; } p;
            p.h[0] = (__bf16)dy; p.h[1] = (__bf16)dx;
            dxyr[cc] = p.u;
        }
    }

    f32x4 acc[3][8] = {};
    fx4 g0[4], g1[4];
    float w0, w1;

    auto load_pair = [&](uint32_t pk, int kk) {
        union { uint32_t u; __bf16 h[2]; } p; p.u = pk;
        float dy = (float)p.h[0], dx = (float)p.h[1];
        float wy  = fmaxf(0.f, 1.f - fabsf(dy));
        float px  = (float)(lb * KW + kk) + dx;
        float x0f = floorf(px);
        float lw  = px - x0f;
        int   i0  = (int)x0f;
        bool valid = (px > -1.0f) && (px < (float)LLEN);
        w0 = (valid && i0 >= 0)         ? (1.f - lw) * wy : 0.f;
        w1 = (valid && (i0 + 1) < LLEN) ? lw * wy         : 0.f;
        int i0c = min(max(i0, 0), LLEN - 1);
        int i1c = min(max(i0 + 1, 0), LLEN - 1);
        const fx4* p0 = (const fx4*)&xb[(size_t)i0c * CCH];
        const fx4* p1 = (const fx4*)&xb[(size_t)i1c * CCH];
#pragma unroll
        for (int q = 0; q < 4; ++q) { g0[q] = p0[q]; g1[q] = p1[q]; }
    };

    if (t < 4 * BM) load_pair(dxyr[0], k4);

#pragma unroll
    for (int cc = 0; cc < 6; ++cc) {
        const int kt = cc * BK;
        __bf16* Ab = As + (cc & 1) * (BM * BK);     // double buffer
        if (t < 4 * BM) {
            bf16x8 oa, ob;
#pragma unroll
            for (int q = 0; q < 2; ++q) {
                fx4 v0 = g0[q], v1 = g1[q];
                oa[q * 4 + 0] = (__bf16)(w0 * v0.x + w1 * v1.x);
                oa[q * 4 + 1] = (__bf16)(w0 * v0.y + w1 * v1.y);
                oa[q * 4 + 2] = (__bf16)(w0 * v0.z + w1 * v1.z);
                oa[q * 4 + 3] = (__bf16)(w0 * v0.w + w1 * v1.w);
            }
#pragma unroll
            for (int q = 0; q < 2; ++q) {
                fx4 v0 = g0[q + 2], v1 = g1[q + 2];
                ob[q * 4 + 0] = (__bf16)(w0 * v0.x + w1 * v1.x);
                ob[q * 4 + 1] = (__bf16)(w0 * v0.y + w1 * v1.y);
                ob[q * 4 + 2] = (__bf16)(w0 * v0.z + w1 * v1.z);
                ob[q * 4 + 3] = (__bf16)(w0 * v0.w + w1 * v1.w);
            }
            int g = 2 * k4;
            *(bf16x8*)&Ab[mloc * BK + ((g ^ (mloc & 7)) * 8)]       = oa;
            *(bf16x8*)&Ab[mloc * BK + (((g + 1) ^ (mloc & 7)) * 8)] = ob;
        }
        __syncthreads();                 // As[cc&1] ready; buf cc^1 free
        if (cc + 1 < 6 && t < 4 * BM)    // prefetch under MFMA
            load_pair(dxyr[cc + 1], 4 * (cc + 1) + k4);
        __builtin_amdgcn_s_setprio(1);
#pragma unroll
        for (int ks = 0; ks < 2; ++ks) {
            bf16x8 af[3], bfr[8];
#pragma unroll
            for (int i = 0; i < 3; ++i) {
                int row = wr * 48 + i * 16 + l16;
                af[i] = *(const bf16x8*)&Ab[row * BK + (((ks * 4 + quad) ^ (row & 7)) * 8)];
            }
#pragma unroll
            for (int j = 0; j < 8; ++j) {
                int col = wc * 128 + j * 16 + l16;   // B direct from L2
                bfr[j] = *(const bf16x8*)&Bw[(size_t)col * CK + kt + (ks * 4 + quad) * 8];
            }
#pragma unroll
            for (int i = 0; i < 3; ++i)
#pragma unroll
                for (int j = 0; j < 8; ++j)
                    acc[i][j] = __builtin_amdgcn_mfma_f32_16x16x32_bf16(
                        af[i], bfr[j], acc[i][j], 0, 0, 0);
        }
        __builtin_amdgcn_s_setprio(0);
    }

    // epilogue: D[row=quad*4+r][col=l16]
#pragma unroll
    for (int j = 0; j < 8; ++j) {
        int col = wc * 128 + j * 16 + l16;
        float bj = bias[col];
#pragma unroll
        for (int i = 0; i < 3; ++i) {
            int rowb = m0 + wr * 48 + i * 16 + quad * 4;
#pragma unroll
            for (int r = 0; r < 4; ++r)
                out[(size_t)(rowb + r) * DOUT + col] = acc[i][j][r] + bj;
        }
    }
}

// ---------------------------------------------------------------------------
extern "C" void kernel_launch(void* const* d_in, const int* in_sizes, int n_in,
                              void* d_out, int out_size, void* d_ws, size_t ws_size,
                              hipStream_t stream)
{
    const float* x     = (const float*)d_in[0];
    const float* w_off = (const float*)d_in[1];
    const float* b_off = (const float*)d_in[2];
    const float* w_def = (const float*)d_in[3];
    const float* b_def = (const float*)d_in[4];
    float* out = (float*)d_out;

    char* ws = (char*)d_ws;
    __bf16* wdef_b = (__bf16*)ws;                 // 393,216 B
    __bf16* woff_b = (__bf16*)(ws + 393216);      //  36,864 B

    prep_kernel<<<768, 256, 0, stream>>>(w_off, w_def, woff_b, wdef_b);
    gemm_fused<<<MROWS / BM, 512, 0, stream>>>(x, woff_b, b_off, wdef_b, b_def, out);
}

// Round 3
// 194.380 us; speedup vs baseline: 1.1698x; 1.1698x over previous
//
#include <hip/hip_runtime.h>
#include <stdint.h>

// Problem constants
#define BATCH 32
#define LLEN  36864
#define CCH   16
#define DOUT  512
#define KW    24
#define LOUT  1536            // LLEN / KW
#define MROWS (BATCH * LOUT)  // 49152 windows
#define CK    384             // CCH * KW (inner dot length)
#define TWOK  48

typedef float fx4 __attribute__((ext_vector_type(4)));
typedef float f32x4 __attribute__((ext_vector_type(4)));
typedef __bf16 bf16x8 __attribute__((ext_vector_type(8)));
typedef uint32_t u32x4 __attribute__((ext_vector_type(4)));

#define VMCNT(n)  asm volatile("s_waitcnt vmcnt(" #n ")" ::: "memory")
#define LGKMCNT0  asm volatile("s_waitcnt lgkmcnt(0)" ::: "memory")
#define SCHEDB    __builtin_amdgcn_sched_barrier(0)
#define SBAR      __builtin_amdgcn_s_barrier()

__device__ __forceinline__ void gload16(void* lds, const void* g)
{
    __builtin_amdgcn_global_load_lds(
        (const __attribute__((address_space(1))) uint32_t*)g,
        (__attribute__((address_space(3))) uint32_t*)lds, 16, 0, 0);
}

// ---------------------------------------------------------------------------
// K0: weight transposition to j = k*16+c layout (bf16).
// ---------------------------------------------------------------------------
__global__ __launch_bounds__(256) void prep_kernel(
    const float* __restrict__ w_off, const float* __restrict__ w_def,
    __bf16* __restrict__ woff_b, __bf16* __restrict__ wdef_b)
{
    int idx = blockIdx.x * 256 + threadIdx.x;
    if (idx < TWOK * CK) {
        int o = idx / CK, rem = idx % CK;
        int k = rem >> 4, c = rem & 15;
        woff_b[idx] = (__bf16)w_off[o * CK + c * KW + k];
    }
    if (idx < DOUT * CK) {
        int d = idx / CK, rem = idx % CK;
        int k = rem >> 4, c = rem & 15;
        wdef_b[idx] = (__bf16)w_def[d * CK + c * KW + k];
    }
}

// ---------------------------------------------------------------------------
// K1: fused offsets + gather + GEMM, T3/T4 pipelined B staging.
// R2 post-mortem: B direct-from-L2 regressed (78.5 -> 111 us) -- fragment
// loads expose L2 latency inside the MFMA dep chain at 4 waves/SIMD.  B must
// stay in LDS; the drain is the problem.  R3: Bs double-buffered at BK=32
// (2 x 32 KB), DMA for phase p+1 issued a full phase ahead, raw s_barrier +
// per-wave counted vmcnt (never a full drain in the loop).  Gather prefetch
// G(cc+1) issued at loop top right after D(2cc+1) so the counted waits
// (12/8 gather waves, 4/0 waves 6-7) keep it in flight across the whole
// iteration.  As single 12 KB buffer (Z barrier covers WAR).  LDS 77,824 B
// -> 2 blocks/CU, same as R0.
// VM queue invariant at loop top: {G(cc):8, D(2cc):4}.
// ---------------------------------------------------------------------------
#define BM 96
#define BN 512
#define BK 64   // per-cc gather granularity; DMA/MFMA phases are BK/2=32

__global__ __launch_bounds__(512) void gemm_fused(
    const float* __restrict__ x, const __bf16* __restrict__ woff_b,
    const float* __restrict__ b_off, const __bf16* __restrict__ Bw,
    const float* __restrict__ bias, float* __restrict__ out)
{
    __shared__ char smem[77824];
    __bf16* As  = (__bf16*)smem;                 // [96][64]  = 12288 B
    __bf16* Bs0 = (__bf16*)(smem + 12288);       // [512][32] = 32768 B
    __bf16* Bs1 = (__bf16*)(smem + 45056);       // [512][32] = 32768 B
    __bf16* WoffS = (__bf16*)smem;               // [48][392] prologue, 37632 B
    float*  offS  = (float*)(smem + 45056);      // [96][49]  prologue, 18816 B
                                                 // (inside Bs1; D(1) issues
                                                 //  only after the Z barrier)

    const int t = threadIdx.x;
    const int m0 = blockIdx.x * BM;
    const int wave = t >> 6, lane = t & 63;
    const int quad = lane >> 4, l16 = lane & 15;
    const int wr = wave >> 2, wc = wave & 3;        // 2x4 waves: tile 48x128

    // gather ownership (threads 0..383): row mloc, k-slot k4 (+4 per chunk)
    const int mloc = t >> 2, k4 = t & 3;
    const int Mrow = m0 + mloc;
    const int b    = m0 / LOUT;                     // 1536 % 96 == 0
    const int lb   = Mrow - b * LOUT;
    const float* xb = x + (size_t)b * LLEN * CCH;

    // ---- prologue: stage woff ----
#pragma unroll
    for (int i = 0; i < 5; ++i) {
        int q = t + 512 * i;                        // 2304 16B chunks
        if (q < 2304) {
            int row = q / 48, cc = q - row * 48;
            *(u32x4*)&WoffS[row * 392 + cc * 8] =
                *(const u32x4*)&woff_b[row * CK + cc * 8];
        }
    }
    __syncthreads();

    // ---- prologue: offsets MFMA (waves 0..5 cover 96 rows) ----
    if (wave < 6) {
        const float* xr = x + (size_t)(m0 + wave * 16 + l16) * CK;
        f32x4 oacc[3] = {};
#pragma unroll
        for (int ks = 0; ks < 12; ++ks) {
            int k0 = ks * 32 + quad * 8;
            fx4 a0 = *(const fx4*)&xr[k0];
            fx4 a1 = *(const fx4*)&xr[k0 + 4];
            bf16x8 af;
            af[0] = (__bf16)a0.x; af[1] = (__bf16)a0.y;
            af[2] = (__bf16)a0.z; af[3] = (__bf16)a0.w;
            af[4] = (__bf16)a1.x; af[5] = (__bf16)a1.y;
            af[6] = (__bf16)a1.z; af[7] = (__bf16)a1.w;
#pragma unroll
            for (int j = 0; j < 3; ++j) {
                bf16x8 bf = *(const bf16x8*)&WoffS[(j * 16 + l16) * 392 + k0];
                oacc[j] = __builtin_amdgcn_mfma_f32_16x16x32_bf16(af, bf, oacc[j], 0, 0, 0);
            }
        }
        float bo[3];
#pragma unroll
        for (int j = 0; j < 3; ++j) bo[j] = b_off[j * 16 + l16];
#pragma unroll
        for (int j = 0; j < 3; ++j)
#pragma unroll
            for (int r = 0; r < 4; ++r)
                offS[(wave * 16 + quad * 4 + r) * 49 + j * 16 + l16] = oacc[j][r] + bo[j];
    }
    __syncthreads();

    // ---- prologue: pack this thread's 6 (dy,dx) pairs into regs ----
    uint32_t dxyr[6];
    if (t < 4 * BM) {
#pragma unroll
        for (int cc = 0; cc < 6; ++cc) {
            int kk = 4 * cc + k4;
            float dy = offS[mloc * 49 + 2 * kk];
            float dx = offS[mloc * 49 + 2 * kk + 1];
            union { __bf16 h[2]; uint32_t u; } p;
            p.h[0] = (__bf16)dy; p.h[1] = (__bf16)dx;
            dxyr[cc] = p.u;
        }
    }

    f32x4 acc[3][8] = {};
    fx4 g0[4], g1[4];
    float w0, w1;

    auto load_pair = [&](uint32_t pk, int kk) {
        union { uint32_t u; __bf16 h[2]; } p; p.u = pk;
        float dy = (float)p.h[0], dx = (float)p.h[1];
        float wy  = fmaxf(0.f, 1.f - fabsf(dy));
        float px  = (float)(lb * KW + kk) + dx;
        float x0f = floorf(px);
        float lw  = px - x0f;
        int   i0  = (int)x0f;
        bool valid = (px > -1.0f) && (px < (float)LLEN);
        w0 = (valid && i0 >= 0)         ? (1.f - lw) * wy : 0.f;
        w1 = (valid && (i0 + 1) < LLEN) ? lw * wy         : 0.f;
        int i0c = min(max(i0, 0), LLEN - 1);
        int i1c = min(max(i0 + 1, 0), LLEN - 1);
        const fx4* p0 = (const fx4*)&xb[(size_t)i0c * CCH];
        const fx4* p1 = (const fx4*)&xb[(size_t)i1c * CCH];
#pragma unroll
        for (int q = 0; q < 4; ++q) { g0[q] = p0[q]; g1[q] = p1[q]; }
    };

    // DMA one BK=32 phase (32 KB) into buf: 2048 chunks / 512 thr = 4 each.
    // LDS dest linear in chunk index (wave-uniform base + lane*16); source
    // carries the XOR swizzle slot s^((c>>1)&3) so ds_read is conflict-free.
    auto dma_phase = [&](int ph, __bf16* buf) {
#pragma unroll
        for (int it = 0; it < 4; ++it) {
            int q = it * 512 + t;
            int c = q >> 2, s = q & 3;
            int ss = s ^ ((c >> 1) & 3);
            gload16(&buf[q * 8], Bw + (size_t)c * CK + ph * 32 + ss * 8);
        }
    };

    auto mfma_phase = [&](int ks, const __bf16* Bsb) {
        bf16x8 af[3], bfr[8];
#pragma unroll
        for (int i = 0; i < 3; ++i) {
            int row = wr * 48 + i * 16 + l16;
            af[i] = *(const bf16x8*)&As[row * BK + (((ks * 4 + quad) ^ (row & 7)) * 8)];
        }
#pragma unroll
        for (int j = 0; j < 8; ++j) {
            int col = wc * 128 + j * 16 + l16;
            bfr[j] = *(const bf16x8*)&Bsb[col * 32 + ((quad ^ ((col >> 1) & 3)) * 8)];
        }
#pragma unroll
        for (int i = 0; i < 3; ++i)
#pragma unroll
            for (int j = 0; j < 8; ++j)
                acc[i][j] = __builtin_amdgcn_mfma_f32_16x16x32_bf16(
                    af[i], bfr[j], acc[i][j], 0, 0, 0);
    };

    // ---- prologue issues: G(0) then D(0) (queue order matters) ----
    if (t < 4 * BM) load_pair(dxyr[0], k4);     // G(0): 8 loads
    SCHEDB;
    dma_phase(0, Bs0);                          // D(0): 4 loads
    SCHEDB;

#pragma unroll
    for (int cc = 0; cc < 6; ++cc) {
        SBAR;                                   // Z: As free (prev readers done)
        SCHEDB;
        VMCNT(4);                               // G(cc) done (trivial for w6,7)
        SCHEDB;
        if (t < 4 * BM) {                       // pack As from g-regs
            bf16x8 oa, ob;
#pragma unroll
            for (int q = 0; q < 2; ++q) {
                fx4 v0 = g0[q], v1 = g1[q];
                oa[q * 4 + 0] = (__bf16)(w0 * v0.x + w1 * v1.x);
                oa[q * 4 + 1] = (__bf16)(w0 * v0.y + w1 * v1.y);
                oa[q * 4 + 2] = (__bf16)(w0 * v0.z + w1 * v1.z);
                oa[q * 4 + 3] = (__bf16)(w0 * v0.w + w1 * v1.w);
            }
#pragma unroll
            for (int q = 0; q < 2; ++q) {
                fx4 v0 = g0[q + 2], v1 = g1[q + 2];
                ob[q * 4 + 0] = (__bf16)(w0 * v0.x + w1 * v1.x);
                ob[q * 4 + 1] = (__bf16)(w0 * v0.y + w1 * v1.y);
                ob[q * 4 + 2] = (__bf16)(w0 * v0.z + w1 * v1.z);
                ob[q * 4 + 3] = (__bf16)(w0 * v0.w + w1 * v1.w);
            }
            int g = 2 * k4;
            *(bf16x8*)&As[mloc * BK + ((g ^ (mloc & 7)) * 8)]       = oa;
            *(bf16x8*)&As[mloc * BK + (((g + 1) ^ (mloc & 7)) * 8)] = ob;
        }
        SCHEDB;
        dma_phase(2 * cc + 1, Bs1);             // D(2cc+1) BEFORE G(cc+1)!
        SCHEDB;
        if (cc + 1 < 6 && t < 4 * BM)
            load_pair(dxyr[cc + 1], 4 * (cc + 1) + k4);   // G(cc+1): 8 loads
        SCHEDB;
        LGKMCNT0;                               // own As ds_writes done
        SCHEDB;
        SBAR;                                   // A: As visible to all
        SCHEDB;
        // wait own D(2cc): gather queue {D4,D4,G8(,..)} -> <=12; w6,7 -> <=4
        if (cc < 5) { if (wave < 6) { VMCNT(12); } else { VMCNT(4); } }
        else        { VMCNT(4); }               // cc=5: no G in queue
        SCHEDB;
        SBAR;                                   // C0: Bs0 ready (all waves)
        SCHEDB;
        __builtin_amdgcn_s_setprio(1);
        mfma_phase(0, Bs0);
        __builtin_amdgcn_s_setprio(0);
        SCHEDB;
        // wait own D(2cc+1): gather {D4,G8} -> <=8; w6,7 -> 0
        if (cc < 5) { if (wave < 6) { VMCNT(8); } else { VMCNT(0); } }
        else        { VMCNT(0); }
        SCHEDB;
        SBAR;                                   // BC1: Bs1 ready; Bs0 free
        SCHEDB;
        if (cc < 5) dma_phase(2 * cc + 2, Bs0); // D(2cc+2), flies under MFMA
        SCHEDB;
        __builtin_amdgcn_s_setprio(1);
        mfma_phase(1, Bs1);
        __builtin_amdgcn_s_setprio(0);
        SCHEDB;
    }

    // epilogue: D[row=quad*4+r][col=l16]
#pragma unroll
    for (int j = 0; j < 8; ++j) {
        int col = wc * 128 + j * 16 + l16;
        float bj = bias[col];
#pragma unroll
        for (int i = 0; i < 3; ++i) {
            int rowb = m0 + wr * 48 + i * 16 + quad * 4;
#pragma unroll
            for (int r = 0; r < 4; ++r)
                out[(size_t)(rowb + r) * DOUT + col] = acc[i][j][r] + bj;
        }
    }
}

// ---------------------------------------------------------------------------
extern "C" void kernel_launch(void* const* d_in, const int* in_sizes, int n_in,
                              void* d_out, int out_size, void* d_ws, size_t ws_size,
                              hipStream_t stream)
{
    const float* x     = (const float*)d_in[0];
    const float* w_off = (const float*)d_in[1];
    const float* b_off = (const float*)d_in[2];
    const float* w_def = (const float*)d_in[3];
    const float* b_def = (const float*)d_in[4];
    float* out = (float*)d_out;

    char* ws = (char*)d_ws;
    __bf16* wdef_b = (__bf16*)ws;                 // 393,216 B
    __bf16* woff_b = (__bf16*)(ws + 393216);      //  36,864 B

    prep_kernel<<<768, 256, 0, stream>>>(w_off, w_def, woff_b, wdef_b);
    gemm_fused<<<MROWS / BM, 512, 0, stream>>>(x, woff_b, b_off, wdef_b, b_def, out);
}